// Round 1
// 378.318 us; speedup vs baseline: 1.0769x; 1.0769x over previous
//
#include <hip/hip_runtime.h>

typedef unsigned int u32;
typedef signed char  i8;

#define BM 256
#define BN 256
#define BK 128

typedef __attribute__((ext_vector_type(4))) int   i32x4;
typedef __attribute__((ext_vector_type(4))) float f4v;

// ============================================================
// Fused quantizer, one dispatch:
//   blocks [0, xblocks)      : per-row int8 quantization of x, scale = absmax/127
//   blocks [xblocks, total)  : sign(w) -> int8 in {-1,0,+1}, fully coalesced
//                              (per-thread chunks at stride 256, NOT consecutive)
// ============================================================
__global__ void __launch_bounds__(256) quant_fused(
    const f4v* __restrict__ x, const f4v* __restrict__ w,
    i8* __restrict__ xq, i8* __restrict__ wq, float* __restrict__ s,
    int K, int xblocks)
{
    const int t    = threadIdx.x;
    const int lane = t & 63;
    const int wave = t >> 6;

    if ((int)blockIdx.x < xblocks) {
        const int row = blockIdx.x;
        const f4v* xr = x + (size_t)row * (K >> 2);
        f4v v[4];
        float amax = 0.f;
#pragma unroll
        for (int c = 0; c < 4; ++c) {
            v[c] = __builtin_nontemporal_load(&xr[t + c * 256]);
            amax = fmaxf(amax, fmaxf(fmaxf(fabsf(v[c].x), fabsf(v[c].y)),
                                     fmaxf(fabsf(v[c].z), fabsf(v[c].w))));
        }
#pragma unroll
        for (int off = 32; off > 0; off >>= 1)
            amax = fmaxf(amax, __shfl_down(amax, off));
        __shared__ float red[4];
        if (lane == 0) red[wave] = amax;
        __syncthreads();
        amax = fmaxf(fmaxf(red[0], red[1]), fmaxf(red[2], red[3]));

        const float inv = (amax > 0.f) ? (127.0f / amax) : 0.f;
        if (t == 0) s[row] = amax * (1.0f / 127.0f);

        i8* xo = xq + (size_t)row * K;
#pragma unroll
        for (int c = 0; c < 4; ++c) {
            const int e = (t + c * 256) * 4;
            int q0 = __float2int_rn(v[c].x * inv);
            int q1 = __float2int_rn(v[c].y * inv);
            int q2 = __float2int_rn(v[c].z * inv);
            int q3 = __float2int_rn(v[c].w * inv);
            u32 p = (q0 & 0xFF) | ((q1 & 0xFF) << 8) |
                    ((q2 & 0xFF) << 16) | ((u32)(q3 & 0xFF) << 24);
            *(u32*)&xo[e] = p;
        }
    } else {
        // block covers 4096 floats of w; thread t handles f4v chunks
        // t, t+256, t+512, t+768 -> every load is lane-contiguous 16B.
        const int b = blockIdx.x - xblocks;
        const f4v* wb = w + (size_t)b * 1024;
        u32* wo = (u32*)(wq + (size_t)b * 4096);
#pragma unroll
        for (int c = 0; c < 4; ++c) {
            const int idx = t + c * 256;
            f4v a = __builtin_nontemporal_load(&wb[idx]);
            u32 b0 = (a.x > 0.f) ? 1u : ((a.x < 0.f) ? 0xFFu : 0u);
            u32 b1 = (a.y > 0.f) ? 1u : ((a.y < 0.f) ? 0xFFu : 0u);
            u32 b2 = (a.z > 0.f) ? 1u : ((a.z < 0.f) ? 0xFFu : 0u);
            u32 b3 = (a.w > 0.f) ? 1u : ((a.w < 0.f) ? 0xFFu : 0u);
            wo[idx] = b0 | (b1 << 8) | (b2 << 16) | (b3 << 24);
        }
    }
}

// async 16B global -> LDS (LDS dest is wave-uniform base + lane*16)
__device__ __forceinline__ void async_cp16(const void* gp, void* lp) {
    __builtin_amdgcn_global_load_lds(
        (__attribute__((address_space(1))) void*)(gp),
        (__attribute__((address_space(3))) void*)(lp),
        16, 0, 0);
}

#define FENCE() asm volatile("" ::: "memory")

// ============================================================
// C[M,N] = (xq . wq^T) * s[row] + bias[col]  -- i8 MFMA, i32 acc
//
// 256x256 tile, BK=128, 8 waves (2M x 4N), double-buffered 128KB LDS,
// counted-vmcnt pipeline (T3/T4-min):
//   per tile: [compute 64 MFMA from buf cur] barrier
//             [stage tile t+2 into buf cur]  s_waitcnt vmcnt(8)  barrier
// The 8 global_load_lds for tile t+1 were issued one full compute phase
// (~2600 cyc) earlier -> vmcnt(8) is a no-op in steady state; loads are
// never drained to 0 inside the loop.
//
// Swizzle (proven 0-conflict in previous version, identical geometry):
// LDS row = 128B = 8 x 16B chunks; LDS chunk q of row r holds global
// chunk q^(r&7); realized by pre-swizzling the per-lane GLOBAL address
// (global_load_lds forces LDS chunk = base+lane*16). Readers XOR back:
// fragment (row, chunk ks*4+quad) -> LDS byte row*128 + ((ks*4+quad)^(row&7))*16.
// ============================================================
__global__ void __launch_bounds__(512, 2) gemm_i8_bt(
    const i8* __restrict__ A, const i8* __restrict__ B,
    const float* __restrict__ s, const float* __restrict__ bias,
    float* __restrict__ C, int M, int N, int K)
{
    extern __shared__ i8 lds[];   // [2][ A:32KB | B:32KB ] = 128 KB

    const int t    = threadIdx.x;
    const int lane = t & 63;
    const int wave = t >> 6;
    const int wm   = (wave >> 2) * 128;   // 2 waves in M, 128 rows each
    const int wn   = (wave & 3) * 64;     // 4 waves in N, 64 cols each
    const int l15  = lane & 15;
    const int quad = lane >> 4;
    const int sw   = l15 & 7;             // reader swizzle key (row&7)

    // XCD-aware decode: 512 blocks, xcd = bid&7, 8x8 patch per XCD (bijective)
    const int nbm = M / BM, nbn = N / BN;
    int mb, nb;
    const int bid = blockIdx.x;
    if (nbm == 32 && nbn == 16) {
        const int xcd   = bid & 7;
        const int local = bid >> 3;            // 64 blocks per XCD
        mb = ((xcd >> 1) << 3) + (local >> 3);
        nb = ((xcd & 1) << 3) + (local & 7);
    } else {
        mb = bid / nbn;
        nb = bid - mb * nbn;
    }
    const size_t m_block = (size_t)mb * BM;
    const size_t n_block = (size_t)nb * BN;

    i32x4 acc[8][4];
#pragma unroll
    for (int i = 0; i < 8; ++i)
#pragma unroll
        for (int j = 0; j < 4; ++j)
            acc[i][j] = (i32x4){0, 0, 0, 0};

    // staging map: each half (A or B) = 256 rows x 128B = 2048 x 16B chunks;
    // thread covers chunks c = t + s*512. LDS chunk c <- global
    // (row = c>>3, chunk (c&7)^(row&7)). 32-bit offsets keep VGPR low.
    const i8* Abase = A + m_block * K;
    const i8* Bbase = B + n_block * K;
    u32 offG[4], lofs[4];
#pragma unroll
    for (int sidx = 0; sidx < 4; ++sidx) {
        const int c  = t + sidx * 512;
        const int r  = c >> 3;
        const int gq = (c & 7) ^ (r & 7);
        lofs[sidx] = (u32)c * 16u;
        offG[sidx] = (u32)(r * K + gq * 16);
    }

    const int NT = K / BK;   // 32

#define STAGE(buf, kofs)                                                    \
    do {                                                                    \
        i8* lbA = lds + (buf) * 65536;                                      \
        i8* lbB = lbA + 32768;                                              \
        _Pragma("unroll")                                                   \
        for (int s_ = 0; s_ < 4; ++s_)                                      \
            async_cp16(Abase + offG[s_] + (kofs), lbA + lofs[s_]);          \
        _Pragma("unroll")                                                   \
        for (int s_ = 0; s_ < 4; ++s_)                                      \
            async_cp16(Bbase + offG[s_] + (kofs), lbB + lofs[s_]);          \
    } while (0)

    // prologue: fill both buffers; wait only for buffer 0 (oldest 8 loads)
    STAGE(0, 0);
    STAGE(1, BK);
    asm volatile("s_waitcnt vmcnt(8)" ::: "memory");
    __builtin_amdgcn_s_barrier();
    FENCE();

    for (int tile = 0; tile < NT; ++tile) {
        const int cur = tile & 1;
        const i8* Abuf = lds + cur * 65536;
        const i8* Bbuf = Abuf + 32768;

#pragma unroll
        for (int ks = 0; ks < 2; ++ks) {
            const int cq = ((ks * 4 + quad) ^ sw) * 16;
            i32x4 af[8], bf[4];
#pragma unroll
            for (int nj = 0; nj < 4; ++nj)
                bf[nj] = *(const i32x4*)&Bbuf[(u32)(wn + nj * 16 + l15) * BK + cq];
#pragma unroll
            for (int mi = 0; mi < 8; ++mi)
                af[mi] = *(const i32x4*)&Abuf[(u32)(wm + mi * 16 + l15) * BK + cq];
#pragma unroll
            for (int mi = 0; mi < 8; ++mi)
#pragma unroll
                for (int nj = 0; nj < 4; ++nj)
                    acc[mi][nj] = __builtin_amdgcn_mfma_i32_16x16x64_i8(
                        af[mi], bf[nj], acc[mi][nj], 0, 0, 0);
        }

        FENCE();
        __builtin_amdgcn_s_barrier();      // all waves done READING buf[cur]
        FENCE();
        if (tile + 2 < NT) {
            STAGE(cur, (tile + 2) * BK);   // overwrite just-consumed buffer
            asm volatile("s_waitcnt vmcnt(8)" ::: "memory");  // tile+1 landed
        } else {
            asm volatile("s_waitcnt vmcnt(0)" ::: "memory");  // drain at end
        }
        __builtin_amdgcn_s_barrier();      // buf[cur^1] fully staged
        FENCE();
    }
#undef STAGE

    // epilogue: C/D layout col=lane&15, row=quad*4+reg (dtype-independent)
    float bv[4];
#pragma unroll
    for (int nj = 0; nj < 4; ++nj)
        bv[nj] = bias[n_block + wn + nj * 16 + l15];

#pragma unroll
    for (int mi = 0; mi < 8; ++mi) {
        const size_t row0 = m_block + wm + mi * 16 + quad * 4;
        const f4v sv = *(const f4v*)&s[row0];
#pragma unroll
        for (int nj = 0; nj < 4; ++nj) {
            const size_t col = n_block + wn + nj * 16 + l15;
            __builtin_nontemporal_store((float)acc[mi][nj][0] * sv.x + bv[nj], &C[(row0 + 0) * N + col]);
            __builtin_nontemporal_store((float)acc[mi][nj][1] * sv.y + bv[nj], &C[(row0 + 1) * N + col]);
            __builtin_nontemporal_store((float)acc[mi][nj][2] * sv.z + bv[nj], &C[(row0 + 2) * N + col]);
            __builtin_nontemporal_store((float)acc[mi][nj][3] * sv.w + bv[nj], &C[(row0 + 3) * N + col]);
        }
    }
}

extern "C" void kernel_launch(void* const* d_in, const int* in_sizes, int n_in,
                              void* d_out, int out_size, void* d_ws, size_t ws_size,
                              hipStream_t stream) {
    const float* x  = (const float*)d_in[0];   // [M,K]
    const float* w  = (const float*)d_in[1];   // [N,K]
    const float* bs = (const float*)d_in[2];   // [N]
    float* out = (float*)d_out;                // [M,N]

    const int N = in_sizes[2];
    const int K = in_sizes[1] / N;
    const int M = in_sizes[0] / K;

    i8*    xq = (i8*)d_ws;                          // [M,K] int8
    i8*    wq = xq + (size_t)M * K;                 // [N,K] int8 (+-1)
    float* s  = (float*)(wq + (size_t)N * K);       // [M] fp32 row scales

    const int xblocks = M;
    const int wblocks = (int)(((size_t)N * K) / (256 * 16));
    quant_fused<<<xblocks + wblocks, 256, 0, stream>>>(
        (const f4v*)x, (const f4v*)w, xq, wq, s, K, xblocks);

    // 128 KB dynamic LDS needs the opt-in (static limit is 64 KB).
    static bool lds_opt_in = false;
    if (!lds_opt_in) {
        hipFuncSetAttribute((const void*)gemm_i8_bt,
                            hipFuncAttributeMaxDynamicSharedMemorySize, 131072);
        lds_opt_in = true;
    }
    const int nblocks = (M / BM) * (N / BN);   // 512
    gemm_i8_bt<<<nblocks, 512, 131072, stream>>>(xq, wq, s, bs, out, M, N, K);
}